// Round 4
// baseline (1030.148 us; speedup 1.0000x reference)
//
#include <hip/hip_runtime.h>
#include <math.h>

#define N_NODES 50000
#define N_EDGES 800000
#define IN_C    256
#define HID     96
#define OUT_C   64
#define NLAYER  3

// ---------------- CSR build ----------------
// NOTE: harness passes integer inputs as int32.

__global__ void k_init(int* cnt, int* cur, int* counter,
                       int* col, float* wgt, int n) {
    int v = blockIdx.x * blockDim.x + threadIdx.x;
    if (v < n) { cnt[v] = 0; cur[v] = 0; }
    if (v == 0) *counter = 0;
    if (v < 8) { col[N_EDGES + v] = 0; wgt[N_EDGES + v] = 0.f; }  // pad for unroll-8 overread
}

__global__ void k_count(const int* __restrict__ ei, int* cnt, int e) {
    int i = blockIdx.x * blockDim.x + threadIdx.x;
    if (i < e) atomicAdd(&cnt[ei[e + i]], 1);   // row 1 = dst
}

__global__ void k_node(const int* __restrict__ cnt, float* __restrict__ dis,
                       int* __restrict__ start, int* counter, int n) {
    int v = blockIdx.x * blockDim.x + threadIdx.x;
    if (v < n) {
        int c = cnt[v];
        dis[v] = (float)(1.0 / sqrt((double)(c + 1)));  // deg incl self-loop >= 1
        start[v] = atomicAdd(counter, c);
    }
}

__global__ void k_fill(const int* __restrict__ ei, const float* __restrict__ dis,
                       const int* __restrict__ start, int* __restrict__ cur,
                       int* __restrict__ col, float* __restrict__ wgt, int e) {
    int i = blockIdx.x * blockDim.x + threadIdx.x;
    if (i < e) {
        int s = ei[i];
        int d = ei[e + i];
        int slot = start[d] + atomicAdd(&cur[d], 1);
        col[slot] = s;
        wgt[slot] = dis[s] * dis[d];
    }
}

// ---------------- dense GEMM: C[N x NOUT] = A[N x KTOT] @ W[KTOT x NOUT] ------
// 64-node groups, per-thread 4 nodes x 4 outputs, K-chunked so LDS stays small
// (>=4 blocks/CU, all 782 blocks co-resident -> latency hidden by waves).
// A is split at K1: cols [0,K1) from A1 (stride lda), [K1,KTOT) from A2 (stride HID).
// WRITEQ: also emit Cq = dithered-quantize(C) (moves quant VALU out of conv GEMM).

template<int KTOT, int KC, int NOUT, bool BIAS, bool WRITEQ>
__global__ __launch_bounds__((NOUT / 4) * 16) void k_gemm(
    const float* __restrict__ A1, int lda, int K1,
    const float* __restrict__ A2,
    const float* __restrict__ W, const float* __restrict__ bias,
    const float* __restrict__ bn, float delta, float inv_delta,
    float* __restrict__ C, float* __restrict__ Cq)
{
    constexpr int OG    = NOUT / 4;
    constexpr int BLOCK = OG * 16;
    constexpr int XSTR  = KC + 4;          // keeps 16B alignment, breaks pow2 stride
    __shared__ float Ws[KC * NOUT];
    __shared__ float xs[64 * XSTR];

    const int t    = threadIdx.x;
    const int og   = t % OG;
    const int rg   = t / OG;
    const int base = blockIdx.x * 64;

    float acc[4][4];
    #pragma unroll
    for (int r = 0; r < 4; r++)
        #pragma unroll
        for (int o = 0; o < 4; o++) acc[r][o] = 0.f;

    #pragma unroll
    for (int ch = 0; ch < KTOT / KC; ch++) {
        const int kc0 = ch * KC;
        const float* Asrc = A1;
        int acol = kc0, alda = lda;
        if (kc0 >= K1) { Asrc = A2; acol = kc0 - K1; alda = HID; }
        __syncthreads();
        // stage W chunk
        for (int i = t; i < KC * OG; i += BLOCK) {
            int k = i / OG, oq = i % OG;
            *(float4*)&Ws[k * NOUT + 4 * oq] =
                *(const float4*)&W[(size_t)(kc0 + k) * NOUT + 4 * oq];
        }
        // stage 64 node-row chunks
        for (int i = t; i < 64 * (KC / 4); i += BLOCK) {
            int node = i / (KC / 4), kq = i % (KC / 4);
            int gn = base + node;
            float4 v = make_float4(0.f, 0.f, 0.f, 0.f);
            if (gn < N_NODES)
                v = *(const float4*)&Asrc[(size_t)gn * alda + acol + 4 * kq];
            *(float4*)&xs[node * XSTR + 4 * kq] = v;
        }
        __syncthreads();
        #pragma unroll
        for (int k = 0; k < KC; k += 4) {
            float4 w0 = *(const float4*)&Ws[(k + 0) * NOUT + 4 * og];
            float4 w1 = *(const float4*)&Ws[(k + 1) * NOUT + 4 * og];
            float4 w2 = *(const float4*)&Ws[(k + 2) * NOUT + 4 * og];
            float4 w3 = *(const float4*)&Ws[(k + 3) * NOUT + 4 * og];
            #pragma unroll
            for (int r = 0; r < 4; r++) {
                float4 xv = *(const float4*)&xs[(4 * rg + r) * XSTR + k];
                acc[r][0] = fmaf(xv.x, w0.x, acc[r][0]);
                acc[r][1] = fmaf(xv.x, w0.y, acc[r][1]);
                acc[r][2] = fmaf(xv.x, w0.z, acc[r][2]);
                acc[r][3] = fmaf(xv.x, w0.w, acc[r][3]);
                acc[r][0] = fmaf(xv.y, w1.x, acc[r][0]);
                acc[r][1] = fmaf(xv.y, w1.y, acc[r][1]);
                acc[r][2] = fmaf(xv.y, w1.z, acc[r][2]);
                acc[r][3] = fmaf(xv.y, w1.w, acc[r][3]);
                acc[r][0] = fmaf(xv.z, w2.x, acc[r][0]);
                acc[r][1] = fmaf(xv.z, w2.y, acc[r][1]);
                acc[r][2] = fmaf(xv.z, w2.z, acc[r][2]);
                acc[r][3] = fmaf(xv.z, w2.w, acc[r][3]);
                acc[r][0] = fmaf(xv.w, w3.x, acc[r][0]);
                acc[r][1] = fmaf(xv.w, w3.y, acc[r][1]);
                acc[r][2] = fmaf(xv.w, w3.z, acc[r][2]);
                acc[r][3] = fmaf(xv.w, w3.w, acc[r][3]);
            }
        }
    }
    // epilogue
    float4 bv = make_float4(0.f, 0.f, 0.f, 0.f);
    if (BIAS) bv = *(const float4*)&bias[4 * og];
    #pragma unroll
    for (int r = 0; r < 4; r++) {
        int gn = base + 4 * rg + r;
        if (gn < N_NODES) {
            float4 c;
            c.x = acc[r][0] + bv.x;
            c.y = acc[r][1] + bv.y;
            c.z = acc[r][2] + bv.z;
            c.w = acc[r][3] + bv.w;
            *(float4*)&C[(size_t)gn * NOUT + 4 * og] = c;
            if (WRITEQ) {
                float4 b = *(const float4*)&bn[(size_t)gn * NOUT + 4 * og];
                float bx = b.x * delta, by = b.y * delta;
                float bz = b.z * delta, bw = b.w * delta;
                float4 q;
                q.x = floorf((c.x + bx) * inv_delta) * delta - bx;
                q.y = floorf((c.y + by) * inv_delta) * delta - by;
                q.z = floorf((c.z + bz) * inv_delta) * delta - bz;
                q.w = floorf((c.w + bw) * inv_delta) * delta - bw;
                *(float4*)&Cq[(size_t)gn * NOUT + 4 * og] = q;
            }
        }
    }
}

// ---------------- h = relu(segment_sum(m) + cb + eps), optionally quantized ---
// float2 lanes (block 48x8), unroll-8 gathers for MLP. QUANT: writes
// h_q for the NEXT layer (bn/delta of layer k+1) -- h itself is never needed.

template<bool QUANT>
__global__ __launch_bounds__(384) void k_agg(
    const float* __restrict__ m, const int* __restrict__ col,
    const float* __restrict__ wgt, const int* __restrict__ start,
    const int* __restrict__ cnt, const float* __restrict__ dis,
    const float* __restrict__ cb, const float* __restrict__ eps,
    const float* __restrict__ bn, float delta, float inv_delta,
    float* __restrict__ hout)
{
    const int tx = threadIdx.x;                    // 0..47, covers elems 2tx,2tx+1
    const int d  = blockIdx.x * 8 + threadIdx.y;   // 6250*8 == N_NODES
    const int s0 = start[d], c = cnt[d];
    const float2* mt = (const float2*)m + tx;      // row stride = 48 float2
    float2 a0 = {0.f, 0.f}, a1 = {0.f, 0.f}, a2 = {0.f, 0.f}, a3 = {0.f, 0.f};
    float2 a4 = {0.f, 0.f}, a5 = {0.f, 0.f}, a6 = {0.f, 0.f}, a7 = {0.f, 0.f};
    for (int e = 0; e < c; e += 8) {
        int i0 = col[s0 + e + 0]; float w0 = (e + 0 < c) ? wgt[s0 + e + 0] : 0.f;
        int i1 = col[s0 + e + 1]; float w1 = (e + 1 < c) ? wgt[s0 + e + 1] : 0.f;
        int i2 = col[s0 + e + 2]; float w2 = (e + 2 < c) ? wgt[s0 + e + 2] : 0.f;
        int i3 = col[s0 + e + 3]; float w3 = (e + 3 < c) ? wgt[s0 + e + 3] : 0.f;
        int i4 = col[s0 + e + 4]; float w4 = (e + 4 < c) ? wgt[s0 + e + 4] : 0.f;
        int i5 = col[s0 + e + 5]; float w5 = (e + 5 < c) ? wgt[s0 + e + 5] : 0.f;
        int i6 = col[s0 + e + 6]; float w6 = (e + 6 < c) ? wgt[s0 + e + 6] : 0.f;
        int i7 = col[s0 + e + 7]; float w7 = (e + 7 < c) ? wgt[s0 + e + 7] : 0.f;
        float2 v0 = mt[(size_t)i0 * 48], v1 = mt[(size_t)i1 * 48];
        float2 v2 = mt[(size_t)i2 * 48], v3 = mt[(size_t)i3 * 48];
        float2 v4 = mt[(size_t)i4 * 48], v5 = mt[(size_t)i5 * 48];
        float2 v6 = mt[(size_t)i6 * 48], v7 = mt[(size_t)i7 * 48];
        a0.x = fmaf(v0.x, w0, a0.x); a0.y = fmaf(v0.y, w0, a0.y);
        a1.x = fmaf(v1.x, w1, a1.x); a1.y = fmaf(v1.y, w1, a1.y);
        a2.x = fmaf(v2.x, w2, a2.x); a2.y = fmaf(v2.y, w2, a2.y);
        a3.x = fmaf(v3.x, w3, a3.x); a3.y = fmaf(v3.y, w3, a3.y);
        a4.x = fmaf(v4.x, w4, a4.x); a4.y = fmaf(v4.y, w4, a4.y);
        a5.x = fmaf(v5.x, w5, a5.x); a5.y = fmaf(v5.y, w5, a5.y);
        a6.x = fmaf(v6.x, w6, a6.x); a6.y = fmaf(v6.y, w6, a6.y);
        a7.x = fmaf(v7.x, w7, a7.x); a7.y = fmaf(v7.y, w7, a7.y);
    }
    float dv = dis[d];
    float sw = dv * dv;
    float2 sv = mt[(size_t)d * 48];
    float ax = ((a0.x + a1.x) + (a2.x + a3.x)) + ((a4.x + a5.x) + (a6.x + a7.x));
    float ay = ((a0.y + a1.y) + (a2.y + a3.y)) + ((a4.y + a5.y) + (a6.y + a7.y));
    ax = fmaf(sv.x, sw, ax);
    ay = fmaf(sv.y, sw, ay);
    float2 cbv = ((const float2*)cb)[tx];
    float2 ev  = ((const float2*)eps)[(size_t)d * 48 + tx];
    float hx = fmaxf(ax + cbv.x + ev.x, 0.f);
    float hy = fmaxf(ay + cbv.y + ev.y, 0.f);
    float2 o;
    if (QUANT) {
        float2 b = ((const float2*)bn)[(size_t)d * 48 + tx];
        float bx = b.x * delta, by = b.y * delta;
        o.x = floorf((hx + bx) * inv_delta) * delta - bx;
        o.y = floorf((hy + by) * inv_delta) * delta - by;
    } else {
        o.x = hx; o.y = hy;
    }
    ((float2*)hout)[(size_t)d * 48 + tx] = o;
}

// ---------------- launch ----------------

extern "C" void kernel_launch(void* const* d_in, const int* in_sizes, int n_in,
                              void* d_out, int out_size, void* d_ws, size_t ws_size,
                              hipStream_t stream) {
    (void)in_sizes; (void)n_in; (void)out_size; (void)ws_size;
    const float* x       = (const float*)d_in[0];
    const int*   ei      = (const int*)d_in[1];     // int32 per harness convention
    const float* proj_w  = (const float*)d_in[2];
    const float* proj_b  = (const float*)d_in[3];
    const float* conv_w  = (const float*)d_in[4];
    const float* conv_b  = (const float*)d_in[5];
    const float* out_w   = (const float*)d_in[6];
    const float* out_b   = (const float*)d_in[7];
    const float* b_noise = (const float*)d_in[8];
    const float* eps_n   = (const float*)d_in[9];
    float*       out     = (float*)d_out;

    char* w = (char*)d_ws;
    size_t off = 0;
    auto alloc = [&](size_t bytes) -> char* {
        char* p = w + off;
        off = (off + bytes + 255) & ~(size_t)255;
        return p;
    };
    float* h0b   = (float*)alloc((size_t)N_NODES * HID * 4);
    float* hq    = (float*)alloc((size_t)N_NODES * HID * 4);  // quantized h (in-place across layers; final h for k_out)
    float* mb    = (float*)alloc((size_t)N_NODES * HID * 4);
    float* dis   = (float*)alloc((size_t)N_NODES * 4);
    float* wgt   = (float*)alloc((size_t)(N_EDGES + 8) * 4);
    int*   col   = (int*)  alloc((size_t)(N_EDGES + 8) * 4);
    int*   cnt   = (int*)  alloc((size_t)N_NODES * 4);
    int*   cur   = (int*)  alloc((size_t)N_NODES * 4);
    int*   start = (int*)  alloc((size_t)N_NODES * 4);
    int*   ctr   = (int*)  alloc(256);

    // CSR build
    k_init <<<(N_NODES + 255) / 256, 256, 0, stream>>>(cnt, cur, ctr, col, wgt, N_NODES);
    k_count<<<(N_EDGES + 255) / 256, 256, 0, stream>>>(ei, cnt, N_EDGES);
    k_node <<<(N_NODES + 255) / 256, 256, 0, stream>>>(cnt, dis, start, ctr, N_NODES);
    k_fill <<<(N_EDGES + 255) / 256, 256, 0, stream>>>(ei, dis, start, cur, col, wgt, N_EDGES);

    const int ngroups = (N_NODES + 63) / 64;    // 782
    const float deltas[NLAYER] = {1.0f, 0.5f, 0.25f};

    // h0 = x @ proj_w + proj_b; also hq0 = quantize(h0, bn[0], delta0)
    // KC=32: LDS = 12288 + 9216 = 21.5 KB -> 4+ blocks/CU
    k_gemm<256, 32, HID, true, true><<<ngroups, 384, 0, stream>>>(
        x, IN_C, 256, nullptr, proj_w, proj_b,
        b_noise, deltas[0], 1.0f / deltas[0], h0b, hq);

    for (int k = 0; k < NLAYER; k++) {
        // m = hq @ conv_w[k]   (KC=48: LDS = 18432 + 13312 = 31.7 KB)
        k_gemm<96, 48, HID, false, false><<<ngroups, 384, 0, stream>>>(
            hq, HID, 96, nullptr, conv_w + (size_t)k * HID * HID, nullptr,
            nullptr, 0.f, 0.f, mb, nullptr);
        // h = relu(agg + cb + eps); layers 0,1 write hq for next layer, layer 2 plain h
        if (k < NLAYER - 1) {
            k_agg<true><<<N_NODES / 8, dim3(48, 8), 0, stream>>>(
                mb, col, wgt, start, cnt, dis,
                conv_b + (size_t)k * HID, eps_n + (size_t)k * N_NODES * HID,
                b_noise + (size_t)(k + 1) * N_NODES * HID,
                deltas[k + 1], 1.0f / deltas[k + 1], hq);
        } else {
            k_agg<false><<<N_NODES / 8, dim3(48, 8), 0, stream>>>(
                mb, col, wgt, start, cnt, dis,
                conv_b + (size_t)k * HID, eps_n + (size_t)k * N_NODES * HID,
                nullptr, 0.f, 0.f, hq);
        }
    }

    // out = concat(h0, h) @ out_w + out_b   (chunks 0,1 from h0b; 2,3 from hq)
    k_gemm<192, 48, OUT_C, true, false><<<ngroups, 256, 0, stream>>>(
        h0b, HID, 96, hq, out_w, out_b,
        nullptr, 0.f, 0.f, out, nullptr);
}